// Round 12
// baseline (1171.741 us; speedup 1.0000x reference)
//
#include <hip/hip_runtime.h>
#include <cstddef>
#include <cstdint>

#define NPTS 2048

typedef short bf16x8 __attribute__((ext_vector_type(8)));
typedef float f32x4 __attribute__((ext_vector_type(4)));

__device__ __forceinline__ unsigned short f2bf(float f) {
  unsigned u = __builtin_bit_cast(unsigned, f);
  unsigned r = u + 0x7fffu + ((u >> 16) & 1u);  // RNE (finite inputs)
  return (unsigned short)(r >> 16);
}
__device__ __forceinline__ float bf2f(unsigned short s) {
  unsigned u = ((unsigned)s) << 16;
  return __builtin_bit_cast(float, u);
}
// float -> order-preserving u32 (handles negatives)
__device__ __forceinline__ unsigned f2sort(float f) {
  unsigned u = __builtin_bit_cast(unsigned, f);
  return u ^ (unsigned)(((int)u >> 31) | 0x80000000);
}

// sorted-4 pool insert (ascending); keys unique
__device__ __forceinline__ void pool_insert(uint64_t k, uint64_t& s0, uint64_t& s1,
                                            uint64_t& s2, uint64_t& s3) {
  s3 = k < s3 ? k : s3;
  uint64_t t;
  t = s2 < s3 ? s2 : s3; s3 = s2 < s3 ? s3 : s2; s2 = t;
  t = s1 < s2 ? s1 : s2; s2 = s1 < s2 ? s2 : s1; s1 = t;
  t = s0 < s1 ? s0 : s1; s1 = s0 < s1 ? s1 : s0; s0 = t;
}

// one extraction round (R7-proven): returns wave-uniform winning m
__device__ __forceinline__ unsigned pool_extract(uint64_t& s0, uint64_t& s1,
                                                 uint64_t& s2, uint64_t& s3, int lane,
                                                 int& cnt) {
  unsigned h32 = (unsigned)(s0 >> 32);
  unsigned wmin = h32;
#pragma unroll
  for (int s = 1; s < 64; s <<= 1)
    wmin = min(wmin, (unsigned)__shfl_xor((int)wmin, s, 64));
  bool own = (h32 == wmin);
  unsigned long long bal = __ballot(own);
  unsigned lo = (unsigned)s0;
  unsigned wlo;
  if (__popcll(bal) > 1) {  // hi-tie (rare): resolve by low word (index)
    unsigned lo2 = own ? lo : 0xFFFFFFFFu;
#pragma unroll
    for (int s = 1; s < 64; s <<= 1)
      lo2 = min(lo2, (unsigned)__shfl_xor((int)lo2, s, 64));
    wlo = lo2;
  } else {
    int owner = __ffsll((unsigned long long)bal) - 1;
    wlo = (unsigned)__shfl((int)lo, owner, 64);
  }
  bool ex = own && (lo == wlo);
  cnt += ex ? 1 : 0;
  s0 = ex ? s1 : s0; s1 = ex ? s2 : s1; s2 = ex ? s3 : s2; s3 = ex ? ~0ull : s3;
  return wlo;
}

// branchless wave-wide u64 min
__device__ __forceinline__ uint64_t wave_min_u64(uint64_t k) {
#pragma unroll
  for (int s = 1; s < 64; s <<= 1) {
    uint64_t ok = __shfl_xor((unsigned long long)k, s, 64);
    k = ok < k ? ok : k;
  }
  return k;
}

// ---------------------------------------------------------------- knn1 + cov (1 query per wave)
__global__ __launch_bounds__(256) void k_knn1_cov(const float* __restrict__ x,
                                                  float* __restrict__ h0) {
  const int b = blockIdx.y;
  const int tid = threadIdx.x;
  const int lane = tid & 63;
  const int w = tid >> 6;
  __shared__ float4 xsq[NPTS];
  const float* xb = x + (size_t)b * NPTS * 3;
  for (int i = tid; i < NPTS; i += 256) {
    float a0 = xb[3 * i], a1 = xb[3 * i + 1], a2 = xb[3 * i + 2];
    xsq[i] = make_float4(a0, a1, a2, fmaf(a0, a0, fmaf(a1, a1, a2 * a2)));
  }
  __syncthreads();
  const int nq = blockIdx.x * 4 + w;
  const float4 q4 = xsq[nq];
  const float sqq = q4.w;
  float d[32];
  uint64_t s0 = ~0ull, s1 = ~0ull, s2 = ~0ull, s3 = ~0ull;
#pragma unroll
  for (int j = 0; j < 32; ++j) {
    float4 v = xsq[j * 64 + lane];
    float dot = q4.x * v.x;
    dot = fmaf(q4.y, v.y, dot);
    dot = fmaf(q4.z, v.z, dot);
    float dd = fmaf(-2.f, dot, sqq + v.w);
    d[j] = dd;
    uint64_t k = ((uint64_t)f2sort(dd) << 32) | (unsigned)(j * 64 + lane);
    pool_insert(k, s0, s1, s2, s3);
  }
  int widx[16];
  int cnt = 0;
#pragma unroll
  for (int r = 0; r < 16; ++r) {
    uint64_t kmin = wave_min_u64(s0);
    widx[r] = (int)(unsigned)kmin;
    bool ex = (s0 == kmin);
    cnt += ex ? 1 : 0;
    s0 = ex ? s1 : s0; s1 = ex ? s2 : s1; s2 = ex ? s3 : s2; s3 = ex ? ~0ull : s3;
  }
  if (__ballot(cnt == 4) != 0ull) {  // rare exact fallback
    unsigned mask = 0;
#pragma unroll
    for (int r = 0; r < 16; ++r) {
      float vmin = 3.4e38f;
      int mmin = 0x7fffffff;
#pragma unroll
      for (int j = 0; j < 32; ++j) {
        bool ok = !((mask >> j) & 1u) && (d[j] < vmin);
        if (ok) { vmin = d[j]; mmin = j * 64 + lane; }
      }
#pragma unroll
      for (int s = 1; s < 64; s <<= 1) {
        float ov = __shfl_xor(vmin, s, 64);
        int om = __shfl_xor(mmin, s, 64);
        if (ov < vmin || (ov == vmin && om < mmin)) { vmin = ov; mmin = om; }
      }
      widx[r] = mmin;
      if (lane == (mmin & 63)) mask |= 1u << (mmin >> 6);
    }
  }
  float sx = 0, sy = 0, sz = 0;
#pragma unroll
  for (int r = 0; r < 16; ++r) {
    float4 v = xsq[widx[r]];
    sx += v.x; sy += v.y; sz += v.z;
  }
  const float mx = sx * 0.0625f, my = sy * 0.0625f, mz = sz * 0.0625f;
  float cxx = 0, cxy = 0, cxz = 0, cyy = 0, cyz = 0, czz = 0;
#pragma unroll
  for (int r = 0; r < 16; ++r) {
    float4 v = xsq[widx[r]];
    float ax = v.x - mx, ay = v.y - my, az = v.z - mz;
    cxx = fmaf(ax, ax, cxx); cxy = fmaf(ax, ay, cxy); cxz = fmaf(ax, az, cxz);
    cyy = fmaf(ay, ay, cyy); cyz = fmaf(ay, az, cyz); czz = fmaf(az, az, czz);
  }
  if (lane == 0) {
    float* o = h0 + ((size_t)b * NPTS + nq) * 12;
    *(float4*)&o[0] = make_float4(q4.x, q4.y, q4.z, cxx);
    *(float4*)&o[4] = make_float4(cxy, cxz, cxy, cyy);
    *(float4*)&o[8] = make_float4(cyz, cxz, cyz, czz);
  }
}

// ---------------------------------------------------------------- MLP1 (12->12->64->64, BN folded) + bf16 plane epilogue
__global__ __launch_bounds__(256) void k_mlp1(
    const float* __restrict__ h0,
    const float* __restrict__ w1, const float* __restrict__ cb1,
    const float* __restrict__ w2, const float* __restrict__ cb2,
    const float* __restrict__ w3, const float* __restrict__ cb3,
    const float* __restrict__ bn1g, const float* __restrict__ bn1b,
    const float* __restrict__ bn1m, const float* __restrict__ bn1v,
    const float* __restrict__ bn2g, const float* __restrict__ bn2b,
    const float* __restrict__ bn2m, const float* __restrict__ bn2v,
    const float* __restrict__ bn3g, const float* __restrict__ bn3b,
    const float* __restrict__ bn3m, const float* __restrict__ bn3v,
    float* __restrict__ h3out,
    unsigned short* __restrict__ h3hi, unsigned short* __restrict__ h3lo) {
  __shared__ float W1[144], W2[768], W3[4096];
  __shared__ float S1[12], F1[12], S2[64], F2[64], S3[64], F3[64];
  __shared__ float h0s[64][12];
  __shared__ float A2[64][65];
  const int tid = threadIdx.x;
  for (int i = tid; i < 144; i += 256) W1[i] = w1[i];
  for (int i = tid; i < 768; i += 256) W2[i] = w2[i];
  for (int i = tid; i < 4096; i += 256) W3[i] = w3[i];
  if (tid < 12) {
    float s = bn1g[tid] * rsqrtf(bn1v[tid] + 1e-3f);
    S1[tid] = s; F1[tid] = (cb1[tid] - bn1m[tid]) * s + bn1b[tid];
  }
  if (tid < 64) {
    float s2 = bn2g[tid] * rsqrtf(bn2v[tid] + 1e-3f);
    S2[tid] = s2; F2[tid] = (cb2[tid] - bn2m[tid]) * s2 + bn2b[tid];
    float s3 = bn3g[tid] * rsqrtf(bn3v[tid] + 1e-3f);
    S3[tid] = s3; F3[tid] = (cb3[tid] - bn3m[tid]) * s3 + bn3b[tid];
  }
  const int p0 = blockIdx.x * 64;
  for (int i = tid; i < 64 * 12; i += 256)
    h0s[i / 12][i % 12] = h0[(size_t)p0 * 12 + i];
  __syncthreads();
  const int pl = tid >> 2;
  const int q = tid & 3;
  float v1[12];
#pragma unroll
  for (int o = 0; o < 12; ++o) {
    float a = 0.f;
#pragma unroll
    for (int i = 0; i < 12; ++i) a = fmaf(h0s[pl][i], W1[i * 12 + o], a);
    v1[o] = fmaxf(fmaf(a, S1[o], F1[o]), 0.f);
  }
#pragma unroll
  for (int o = 0; o < 16; ++o) {
    int oo = q * 16 + o;
    float a = 0.f;
#pragma unroll
    for (int i = 0; i < 12; ++i) a = fmaf(v1[i], W2[i * 64 + oo], a);
    A2[pl][oo] = fmaxf(fmaf(a, S2[oo], F2[oo]), 0.f);
  }
  __syncthreads();
  float acc[16];
#pragma unroll
  for (int o = 0; o < 16; ++o) acc[o] = 0.f;
  for (int i = 0; i < 64; ++i) {
    float xv = A2[pl][i];
#pragma unroll
    for (int o = 0; o < 16; ++o) acc[o] = fmaf(xv, W3[i * 64 + q * 16 + o], acc[o]);
  }
  float vals[16];
#pragma unroll
  for (int o = 0; o < 16; ++o) {
    int oo = q * 16 + o;
    vals[o] = fmaxf(fmaf(acc[o], S3[oo], F3[oo]), 0.f);
  }
  const size_t rowo = (size_t)(p0 + pl) * 64 + q * 16;
  float* orow = h3out + rowo;
#pragma unroll
  for (int o4 = 0; o4 < 4; ++o4)
    *(float4*)&orow[4 * o4] = make_float4(vals[4 * o4], vals[4 * o4 + 1],
                                          vals[4 * o4 + 2], vals[4 * o4 + 3]);
  bf16x8 hv0, hv1, lv0, lv1;
#pragma unroll
  for (int o = 0; o < 8; ++o) {
    unsigned short hb = f2bf(vals[o]);
    hv0[o] = (short)hb; lv0[o] = (short)f2bf(vals[o] - bf2f(hb));
    unsigned short hb1 = f2bf(vals[8 + o]);
    hv1[o] = (short)hb1; lv1[o] = (short)f2bf(vals[8 + o] - bf2f(hb1));
  }
  *(bf16x8*)&h3hi[rowo] = hv0; *(bf16x8*)&h3hi[rowo + 8] = hv1;
  *(bf16x8*)&h3lo[rowo] = lv0; *(bf16x8*)&h3lo[rowo + 8] = lv1;
}

// ---------------------------------------------------------------- sq norms
template <int C>
__global__ __launch_bounds__(256) void k_sqnorm(const float* __restrict__ h,
                                                float* __restrict__ sq) {
  const int p = blockIdx.x * 256 + threadIdx.x;
  const float* row = h + (size_t)p * C;
  float a = 0.f;
#pragma unroll
  for (int i = 0; i < C; ++i) a = fmaf(row[i], row[i], a);
  sq[p] = a;
}

// ---------------------------------------------------------------- MFMA dist GEMM: D[bz][q][m] = sq[q]+sq[m]-2<h_q,h_m>
// output staged via LDS for full-cacheline coalesced stores
template <int C>
__global__ __launch_bounds__(256) void k_dgemm(const unsigned short* __restrict__ hi,
                                               const unsigned short* __restrict__ lo,
                                               const float* __restrict__ sq,
                                               float* __restrict__ Dot, int batch0) {
  __shared__ float Ls[64][132];
  const int tid = threadIdx.x, lane = tid & 63, w = tid >> 6;
  const int bz = blockIdx.z;
  const int b = batch0 + bz;
  const int q0 = blockIdx.x * 64 + w * 16;
  const int m0 = blockIdx.y * 128;
  const size_t base = (size_t)b * NPTS * C;
  const int r = lane & 15, ks = (lane >> 4) * 8;
  const unsigned short* Ah = hi + base + (size_t)(q0 + r) * C + ks;
  const unsigned short* Al = lo + base + (size_t)(q0 + r) * C + ks;
  const unsigned short* Bh = hi + base + (size_t)(m0 + r) * C + ks;
  const unsigned short* Bl = lo + base + (size_t)(m0 + r) * C + ks;
  f32x4 acc[8];
#pragma unroll
  for (int mt = 0; mt < 8; ++mt) acc[mt] = (f32x4){0.f, 0.f, 0.f, 0.f};
#pragma unroll
  for (int kk = 0; kk < C; kk += 32) {
    bf16x8 ah = *(const bf16x8*)(Ah + kk);
    bf16x8 al = *(const bf16x8*)(Al + kk);
#pragma unroll
    for (int mt = 0; mt < 8; ++mt) {
      bf16x8 bh = *(const bf16x8*)(Bh + (size_t)mt * 16 * C + kk);
      bf16x8 bl = *(const bf16x8*)(Bl + (size_t)mt * 16 * C + kk);
      acc[mt] = __builtin_amdgcn_mfma_f32_16x16x32_bf16(ah, bh, acc[mt], 0, 0, 0);
      acc[mt] = __builtin_amdgcn_mfma_f32_16x16x32_bf16(ah, bl, acc[mt], 0, 0, 0);
      acc[mt] = __builtin_amdgcn_mfma_f32_16x16x32_bf16(al, bh, acc[mt], 0, 0, 0);
    }
  }
  const float* __restrict__ sqb = sq + (size_t)b * NPTS;
  float sqq[4];
#pragma unroll
  for (int r2 = 0; r2 < 4; ++r2) sqq[r2] = sqb[q0 + (lane >> 4) * 4 + r2];
#pragma unroll
  for (int mt = 0; mt < 8; ++mt) {
    float smc = sqb[m0 + mt * 16 + (lane & 15)];
#pragma unroll
    for (int r2 = 0; r2 < 4; ++r2)
      Ls[w * 16 + (lane >> 4) * 4 + r2][mt * 16 + (lane & 15)] =
          fmaf(-2.f, acc[mt][r2], sqq[r2] + smc);
  }
  __syncthreads();
  float* Db = Dot + (size_t)bz * NPTS * NPTS + (size_t)(blockIdx.x * 64) * NPTS + m0;
  for (int i = tid; i < 64 * 32; i += 256) {
    int row = i >> 5, c4 = i & 31;
    float4 v = *(const float4*)&Ls[row][c4 * 4];
    *(float4*)&Db[(size_t)row * NPTS + c4 * 4] = v;
  }
}

// ---------------------------------------------------------------- select top16 + gather-max -> bf16 hi/lo planes (R7-proven)
template <int C>
__global__ __launch_bounds__(256) void k_select(const float* __restrict__ Dot,
                                                const float* __restrict__ h,
                                                unsigned short* __restrict__ mhi,
                                                unsigned short* __restrict__ mlo,
                                                int batch0) {
  const int tid = threadIdx.x, lane = tid & 63, w = tid >> 6;
  const int bz = blockIdx.y, b = batch0 + bz;
  const int q = blockIdx.x * 4 + w;
  const size_t hb = (size_t)b * NPTS * C;
  const float* __restrict__ hbp = h + hb;
  const float* __restrict__ Drow = Dot + (size_t)bz * NPTS * NPTS + (size_t)q * NPTS;
  float d[32];
  uint64_t s0 = ~0ull, s1 = ~0ull, s2 = ~0ull, s3 = ~0ull;
#pragma unroll
  for (int t = 0; t < 8; ++t) {
    float4 dv = *(const float4*)&Drow[t * 256 + 4 * lane];
    d[4 * t + 0] = dv.x; d[4 * t + 1] = dv.y;
    d[4 * t + 2] = dv.z; d[4 * t + 3] = dv.w;
  }
#pragma unroll
  for (int j = 0; j < 32; ++j) {
    unsigned m = (unsigned)((j >> 2) * 256 + 4 * lane + (j & 3));
    uint64_t k = ((uint64_t)f2sort(d[j]) << 32) | m;
    pool_insert(k, s0, s1, s2, s3);
  }
  int cnt = 0;
  float g0 = -3.4e38f, g1 = -3.4e38f;
#pragma unroll
  for (int r = 0; r < 16; ++r) {
    unsigned m = pool_extract(s0, s1, s2, s3, lane, cnt);
    const float* row = hbp + (size_t)m * C;
    g0 = fmaxf(g0, row[lane]);
    if (C == 128) g1 = fmaxf(g1, row[64 + lane]);
  }
  if (__ballot(cnt == 4) != 0ull) {  // rare exact fallback
    unsigned mask = 0u;
    g0 = -3.4e38f; g1 = -3.4e38f;
#pragma unroll 1
    for (int r = 0; r < 16; ++r) {
      float vmin = 3.4e38f;
      int mmin = 0x7fffffff;
#pragma unroll
      for (int j = 0; j < 32; ++j) {
        const int m = (j >> 2) * 256 + 4 * lane + (j & 3);
        bool ok = !((mask >> j) & 1u) && (d[j] < vmin);
        if (ok) { vmin = d[j]; mmin = m; }
      }
#pragma unroll
      for (int s = 1; s < 64; s <<= 1) {
        float ov = __shfl_xor(vmin, s, 64);
        int om = __shfl_xor(mmin, s, 64);
        if (ov < vmin || (ov == vmin && om < mmin)) { vmin = ov; mmin = om; }
      }
      if (lane == ((mmin >> 2) & 63)) mask |= 1u << (((mmin >> 8) << 2) | (mmin & 3));
      const float* row = hbp + (size_t)mmin * C;
      g0 = fmaxf(g0, row[lane]);
      if (C == 128) g1 = fmaxf(g1, row[64 + lane]);
    }
  }
  const size_t orow = hb + (size_t)q * C;
  unsigned short h0b = f2bf(g0);
  mhi[orow + lane] = h0b;
  mlo[orow + lane] = f2bf(g0 - bf2f(h0b));
  if (C == 128) {
    unsigned short h1b = f2bf(g1);
    mhi[orow + 64 + lane] = h1b;
    mlo[orow + 64 + lane] = f2bf(g1 - bf2f(h1b));
  }
}

// ---------------------------------------------------------------- combine denses -> W^T bf16 planes + bias
__global__ __launch_bounds__(256) void k_combine_t(const float* __restrict__ lw,
                                                   const float* __restrict__ lb,
                                                   const float* __restrict__ cw,
                                                   const float* __restrict__ cb,
                                                   unsigned short* __restrict__ wthi,
                                                   unsigned short* __restrict__ wtlo,
                                                   float* __restrict__ bc, int K, int M) {
  const int id = blockIdx.x * 256 + threadIdx.x;
  if (id < K * M) {
    int i = id / M, o = id % M;
    float a = 0.f;
    for (int k = 0; k < K; ++k) a = fmaf(lw[i * K + k], cw[k * M + o], a);
    unsigned short hb = f2bf(a);
    wthi[(size_t)o * K + i] = hb;
    wtlo[(size_t)o * K + i] = f2bf(a - bf2f(hb));
  }
  if (id < M) {
    float a = cb[id];
    for (int k = 0; k < K; ++k) a = fmaf(lb[k], cw[k * M + id], a);
    bc[id] = a;
  }
}

// ---------------------------------------------------------------- MFMA apply: out = A[32768,K]*W[K,M]+bias, RELU->f32+planes | COLMAX->P
template <int K, int M, bool RELU, bool COLMAX>
__global__ __launch_bounds__(256) void k_apply_mfma(
    const unsigned short* __restrict__ Ah, const unsigned short* __restrict__ Al,
    const unsigned short* __restrict__ Wh, const unsigned short* __restrict__ Wl,
    const float* __restrict__ bias, float* __restrict__ fout,
    unsigned short* __restrict__ phi, unsigned short* __restrict__ plo) {
  __shared__ float cm[4][128];
  const int tid = threadIdx.x, lane = tid & 63, w = tid >> 6;
  const int rt = blockIdx.x;
  const int q0 = rt * 64 + w * 16;
  const int m0 = blockIdx.y * 128;
  const int r = lane & 15, ks = (lane >> 4) * 8;
  const unsigned short* ap_h = Ah + (size_t)(q0 + r) * K + ks;
  const unsigned short* ap_l = Al + (size_t)(q0 + r) * K + ks;
  const unsigned short* bp_h = Wh + (size_t)(m0 + r) * K + ks;
  const unsigned short* bp_l = Wl + (size_t)(m0 + r) * K + ks;
  f32x4 acc[8];
#pragma unroll
  for (int mt = 0; mt < 8; ++mt) acc[mt] = (f32x4){0.f, 0.f, 0.f, 0.f};
#pragma unroll
  for (int kk = 0; kk < K; kk += 32) {
    bf16x8 ah = *(const bf16x8*)(ap_h + kk);
    bf16x8 al = *(const bf16x8*)(ap_l + kk);
#pragma unroll
    for (int mt = 0; mt < 8; ++mt) {
      bf16x8 bh = *(const bf16x8*)(bp_h + (size_t)mt * 16 * K + kk);
      bf16x8 bl = *(const bf16x8*)(bp_l + (size_t)mt * 16 * K + kk);
      acc[mt] = __builtin_amdgcn_mfma_f32_16x16x32_bf16(ah, bh, acc[mt], 0, 0, 0);
      acc[mt] = __builtin_amdgcn_mfma_f32_16x16x32_bf16(ah, bl, acc[mt], 0, 0, 0);
      acc[mt] = __builtin_amdgcn_mfma_f32_16x16x32_bf16(al, bh, acc[mt], 0, 0, 0);
    }
  }
  if (RELU) {
#pragma unroll
    for (int mt = 0; mt < 8; ++mt) {
      const int col = m0 + mt * 16 + (lane & 15);
      const float bv = bias[col];
#pragma unroll
      for (int r2 = 0; r2 < 4; ++r2) {
        const int row = q0 + (lane >> 4) * 4 + r2;
        float v = fmaxf(acc[mt][r2] + bv, 0.f);
        const size_t idx = (size_t)row * M + col;
        fout[idx] = v;
        unsigned short hb = f2bf(v);
        phi[idx] = hb;
        plo[idx] = f2bf(v - bf2f(hb));
      }
    }
  }
  if (COLMAX) {
#pragma unroll
    for (int mt = 0; mt < 8; ++mt) {
      float v = fmaxf(fmaxf(acc[mt][0], acc[mt][1]), fmaxf(acc[mt][2], acc[mt][3]));
      v = fmaxf(v, __shfl_xor(v, 16, 64));
      v = fmaxf(v, __shfl_xor(v, 32, 64));
      cm[w][mt * 16 + (lane & 15)] = v;
    }
    __syncthreads();
    if (tid < 128) {
      float m = fmaxf(fmaxf(cm[0][tid], cm[1][tid]), fmaxf(cm[2][tid], cm[3][tid]));
      fout[(size_t)rt * M + m0 + tid] = m + bias[m0 + tid];
    }
  }
}

// ---------------------------------------------------------------- reduce P[512][1024] -> gmax[16][1024]
__global__ __launch_bounds__(256) void k_reduce_max(const float* __restrict__ P,
                                                    float* __restrict__ gmax) {
  const int b = blockIdx.x, tid = threadIdx.x;
  for (int c = tid; c < 1024; c += 256) {
    float m = P[(size_t)(b * 32) * 1024 + c];
    for (int rt = 1; rt < 32; ++rt)
      m = fmaxf(m, P[(size_t)(b * 32 + rt) * 1024 + c]);
    gmax[b * 1024 + c] = m;
  }
}

// ---------------------------------------------------------------- head part 1: hid = relu(gmax*W4+b4)
__global__ __launch_bounds__(256) void k_head1(const float* __restrict__ gmax,
                                               const float* __restrict__ w4,
                                               const float* __restrict__ b4,
                                               float* __restrict__ hid) {
  const int b = blockIdx.y, c0 = blockIdx.x * 64;
  const int tid = threadIdx.x;
  const int c = tid & 63, iq = tid >> 6;
  __shared__ float xs[1024];
  __shared__ float red[4][64];
  for (int i = tid; i < 1024; i += 256) xs[i] = gmax[b * 1024 + i];
  __syncthreads();
  float a = 0.f;
  for (int i = iq * 256; i < iq * 256 + 256; ++i)
    a = fmaf(xs[i], w4[(size_t)i * 1024 + c0 + c], a);
  red[iq][c] = a;
  __syncthreads();
  if (tid < 64) {
    float v = red[0][tid] + red[1][tid] + red[2][tid] + red[3][tid];
    hid[b * 1024 + c0 + tid] = fmaxf(v + b4[c0 + tid], 0.f);
  }
}

// ---------------------------------------------------------------- head part 2: out = hid*W5+b5
__global__ __launch_bounds__(256) void k_head2(const float* __restrict__ hid,
                                               const float* __restrict__ w5,
                                               const float* __restrict__ b5,
                                               float* __restrict__ out) {
  const int b = blockIdx.y, c0 = blockIdx.x * 64;
  const int tid = threadIdx.x;
  const int c = tid & 63, iq = tid >> 6;
  __shared__ float xs[1024];
  __shared__ float red[4][64];
  for (int i = tid; i < 1024; i += 256) xs[i] = hid[b * 1024 + i];
  __syncthreads();
  float a = 0.f;
  for (int i = iq * 256; i < iq * 256 + 256; ++i)
    a = fmaf(xs[i], w5[(size_t)i * 512 + c0 + c], a);
  red[iq][c] = a;
  __syncthreads();
  if (tid < 64) {
    float v = red[0][tid] + red[1][tid] + red[2][tid] + red[3][tid];
    out[(size_t)b * 512 + c0 + tid] = v + b5[c0 + tid];
  }
}

// ----------------------------------------------------------------
extern "C" void kernel_launch(void* const* d_in, const int* in_sizes, int n_in,
                              void* d_out, int out_size, void* d_ws, size_t ws_size,
                              hipStream_t stream) {
  (void)in_sizes; (void)n_in; (void)out_size;
  const float* x = (const float*)d_in[0];
  const float* w1 = (const float*)d_in[1];  const float* b1 = (const float*)d_in[2];
  const float* w2 = (const float*)d_in[3];  const float* b2 = (const float*)d_in[4];
  const float* w3 = (const float*)d_in[5];  const float* b3 = (const float*)d_in[6];
  const float* g1lw = (const float*)d_in[7];  const float* g1lb = (const float*)d_in[8];
  const float* g1cw = (const float*)d_in[9];  const float* g1cb = (const float*)d_in[10];
  const float* g2lw = (const float*)d_in[11]; const float* g2lb = (const float*)d_in[12];
  const float* g2cw = (const float*)d_in[13]; const float* g2cb = (const float*)d_in[14];
  const float* w4 = (const float*)d_in[15]; const float* b4 = (const float*)d_in[16];
  const float* w5 = (const float*)d_in[17]; const float* b5 = (const float*)d_in[18];
  const float* bn1g = (const float*)d_in[19]; const float* bn1b = (const float*)d_in[20];
  const float* bn1m = (const float*)d_in[21]; const float* bn1v = (const float*)d_in[22];
  const float* bn2g = (const float*)d_in[23]; const float* bn2b = (const float*)d_in[24];
  const float* bn2m = (const float*)d_in[25]; const float* bn2v = (const float*)d_in[26];
  const float* bn3g = (const float*)d_in[27]; const float* bn3b = (const float*)d_in[28];
  const float* bn3m = (const float*)d_in[29]; const float* bn3v = (const float*)d_in[30];

  float* ws = (float*)d_ws;
  size_t off = 0;
  auto alloc = [&](size_t n) { float* p = ws + off; off += (n + 63) & ~(size_t)63; return p; };
  float* slotA = alloc(16u * 2048 * 128);   // h0 then h4 f32
  float* slotB = alloc(16u * 2048 * 64);    // h3 f32
  float* sqv  = alloc(16u * 2048);
  unsigned short* hi_h = (unsigned short*)alloc(16u * 2048 * 64);  // h planes
  unsigned short* lo_h = (unsigned short*)alloc(16u * 2048 * 64);
  unsigned short* mhi = (unsigned short*)alloc(16u * 2048 * 64);   // gather-max planes
  unsigned short* mlo = (unsigned short*)alloc(16u * 2048 * 64);
  unsigned short* wthi = (unsigned short*)alloc(65536);            // W^T planes
  unsigned short* wtlo = (unsigned short*)alloc(65536);
  float* bc   = alloc(1024);
  float* P    = alloc(512u * 1024);
  float* gm   = alloc(16u * 1024);
  float* hid  = alloc(16u * 1024);
  int CH = 4;
  while (CH > 1 && (off + (size_t)CH * NPTS * NPTS + 64) * 4 > ws_size) CH >>= 1;
  float* Dot = alloc((size_t)CH * NPTS * NPTS);

  // 1: knn on xyz + covariance -> h0[B,N,12]
  k_knn1_cov<<<dim3(512, 16), 256, 0, stream>>>(x, slotA);
  // 2: MLP1 -> h3 f32 + bf16 planes
  k_mlp1<<<512, 256, 0, stream>>>(slotA, w1, b1, w2, b2, w3, b3,
                                  bn1g, bn1b, bn1m, bn1v,
                                  bn2g, bn2b, bn2m, bn2v,
                                  bn3g, bn3b, bn3m, bn3v, slotB, hi_h, lo_h);
  // 3: knn(64) via dgemm + select -> m1 planes
  k_sqnorm<64><<<128, 256, 0, stream>>>(slotB, sqv);
  for (int c = 0; c < 16; c += CH) {
    int ch = (16 - c) < CH ? (16 - c) : CH;
    k_dgemm<64><<<dim3(32, 16, ch), 256, 0, stream>>>(hi_h, lo_h, sqv, Dot, c);
    k_select<64><<<dim3(512, ch), 256, 0, stream>>>(Dot, slotB, mhi, mlo, c);
  }
  // 4: g1 combined dense 64->128 + relu -> h4 f32 + planes (MFMA)
  k_combine_t<<<32, 256, 0, stream>>>(g1lw, g1lb, g1cw, g1cb, wthi, wtlo, bc, 64, 128);
  k_apply_mfma<64, 128, true, false><<<dim3(512, 1), 256, 0, stream>>>(
      mhi, mlo, wthi, wtlo, bc, slotA, hi_h, lo_h);
  // 5: knn(128) via dgemm + select -> m2 planes
  k_sqnorm<128><<<128, 256, 0, stream>>>(slotA, sqv);
  for (int c = 0; c < 16; c += CH) {
    int ch = (16 - c) < CH ? (16 - c) : CH;
    k_dgemm<128><<<dim3(32, 16, ch), 256, 0, stream>>>(hi_h, lo_h, sqv, Dot, c);
    k_select<128><<<dim3(512, ch), 256, 0, stream>>>(Dot, slotA, mhi, mlo, c);
  }
  // 6: g2 combined dense 128->1024 + colmax -> P (MFMA)
  k_combine_t<<<512, 256, 0, stream>>>(g2lw, g2lb, g2cw, g2cb, wthi, wtlo, bc, 128, 1024);
  k_apply_mfma<128, 1024, false, true><<<dim3(512, 8), 256, 0, stream>>>(
      mhi, mlo, wthi, wtlo, bc, P, nullptr, nullptr);
  // 7: reduce -> gmax[16][1024]
  k_reduce_max<<<16, 256, 0, stream>>>(P, gm);
  // 8: head -> out[16][512]
  k_head1<<<dim3(16, 16), 256, 0, stream>>>(gm, w4, b4, hid);
  k_head2<<<dim3(8, 16), 256, 0, stream>>>(hid, w5, b5, (float*)d_out);
}

// Round 13
// 918.144 us; speedup vs baseline: 1.2762x; 1.2762x over previous
//
#include <hip/hip_runtime.h>
#include <cstddef>
#include <cstdint>

#define NPTS 2048

typedef short bf16x8 __attribute__((ext_vector_type(8)));
typedef float f32x4 __attribute__((ext_vector_type(4)));

__device__ __forceinline__ unsigned short f2bf(float f) {
  unsigned u = __builtin_bit_cast(unsigned, f);
  unsigned r = u + 0x7fffu + ((u >> 16) & 1u);  // RNE (finite inputs)
  return (unsigned short)(r >> 16);
}
__device__ __forceinline__ float bf2f(unsigned short s) {
  unsigned u = ((unsigned)s) << 16;
  return __builtin_bit_cast(float, u);
}
// float -> order-preserving u32 (handles negatives)
__device__ __forceinline__ unsigned f2sort(float f) {
  unsigned u = __builtin_bit_cast(unsigned, f);
  return u ^ (unsigned)(((int)u >> 31) | 0x80000000);
}

// sorted-4 pool insert (ascending); keys unique
__device__ __forceinline__ void pool_insert(uint64_t k, uint64_t& s0, uint64_t& s1,
                                            uint64_t& s2, uint64_t& s3) {
  s3 = k < s3 ? k : s3;
  uint64_t t;
  t = s2 < s3 ? s2 : s3; s3 = s2 < s3 ? s3 : s2; s2 = t;
  t = s1 < s2 ? s1 : s2; s2 = s1 < s2 ? s2 : s1; s1 = t;
  t = s0 < s1 ? s0 : s1; s1 = s0 < s1 ? s1 : s0; s0 = t;
}

// branchless wave-wide u64 min
__device__ __forceinline__ uint64_t wave_min_u64(uint64_t k) {
#pragma unroll
  for (int s = 1; s < 64; s <<= 1) {
    uint64_t ok = __shfl_xor((unsigned long long)k, s, 64);
    k = ok < k ? ok : k;
  }
  return k;
}

__device__ __forceinline__ int mbcnt64(unsigned long long m) {
  return __builtin_amdgcn_mbcnt_hi((unsigned)(m >> 32),
                                   __builtin_amdgcn_mbcnt_lo((unsigned)m, 0));
}

// ---------------------------------------------------------------- knn1 + cov (1 query per wave)
__global__ __launch_bounds__(256) void k_knn1_cov(const float* __restrict__ x,
                                                  float* __restrict__ h0) {
  const int b = blockIdx.y;
  const int tid = threadIdx.x;
  const int lane = tid & 63;
  const int w = tid >> 6;
  __shared__ float4 xsq[NPTS];
  const float* xb = x + (size_t)b * NPTS * 3;
  for (int i = tid; i < NPTS; i += 256) {
    float a0 = xb[3 * i], a1 = xb[3 * i + 1], a2 = xb[3 * i + 2];
    xsq[i] = make_float4(a0, a1, a2, fmaf(a0, a0, fmaf(a1, a1, a2 * a2)));
  }
  __syncthreads();
  const int nq = blockIdx.x * 4 + w;
  const float4 q4 = xsq[nq];
  const float sqq = q4.w;
  float d[32];
  uint64_t s0 = ~0ull, s1 = ~0ull, s2 = ~0ull, s3 = ~0ull;
#pragma unroll
  for (int j = 0; j < 32; ++j) {
    float4 v = xsq[j * 64 + lane];
    float dot = q4.x * v.x;
    dot = fmaf(q4.y, v.y, dot);
    dot = fmaf(q4.z, v.z, dot);
    float dd = fmaf(-2.f, dot, sqq + v.w);
    d[j] = dd;
    uint64_t k = ((uint64_t)f2sort(dd) << 32) | (unsigned)(j * 64 + lane);
    pool_insert(k, s0, s1, s2, s3);
  }
  int widx[16];
  int cnt = 0;
#pragma unroll
  for (int r = 0; r < 16; ++r) {
    uint64_t kmin = wave_min_u64(s0);
    widx[r] = (int)(unsigned)kmin;
    bool ex = (s0 == kmin);
    cnt += ex ? 1 : 0;
    s0 = ex ? s1 : s0; s1 = ex ? s2 : s1; s2 = ex ? s3 : s2; s3 = ex ? ~0ull : s3;
  }
  if (__ballot(cnt == 4) != 0ull) {  // rare exact fallback
    unsigned mask = 0;
#pragma unroll
    for (int r = 0; r < 16; ++r) {
      float vmin = 3.4e38f;
      int mmin = 0x7fffffff;
#pragma unroll
      for (int j = 0; j < 32; ++j) {
        bool ok = !((mask >> j) & 1u) && (d[j] < vmin);
        if (ok) { vmin = d[j]; mmin = j * 64 + lane; }
      }
#pragma unroll
      for (int s = 1; s < 64; s <<= 1) {
        float ov = __shfl_xor(vmin, s, 64);
        int om = __shfl_xor(mmin, s, 64);
        if (ov < vmin || (ov == vmin && om < mmin)) { vmin = ov; mmin = om; }
      }
      widx[r] = mmin;
      if (lane == (mmin & 63)) mask |= 1u << (mmin >> 6);
    }
  }
  float sx = 0, sy = 0, sz = 0;
#pragma unroll
  for (int r = 0; r < 16; ++r) {
    float4 v = xsq[widx[r]];
    sx += v.x; sy += v.y; sz += v.z;
  }
  const float mx = sx * 0.0625f, my = sy * 0.0625f, mz = sz * 0.0625f;
  float cxx = 0, cxy = 0, cxz = 0, cyy = 0, cyz = 0, czz = 0;
#pragma unroll
  for (int r = 0; r < 16; ++r) {
    float4 v = xsq[widx[r]];
    float ax = v.x - mx, ay = v.y - my, az = v.z - mz;
    cxx = fmaf(ax, ax, cxx); cxy = fmaf(ax, ay, cxy); cxz = fmaf(ax, az, cxz);
    cyy = fmaf(ay, ay, cyy); cyz = fmaf(ay, az, cyz); czz = fmaf(az, az, czz);
  }
  if (lane == 0) {
    float* o = h0 + ((size_t)b * NPTS + nq) * 12;
    *(float4*)&o[0] = make_float4(q4.x, q4.y, q4.z, cxx);
    *(float4*)&o[4] = make_float4(cxy, cxz, cxy, cyy);
    *(float4*)&o[8] = make_float4(cyz, cxz, cyz, czz);
  }
}

// ---------------------------------------------------------------- MLP1 (12->12->64->64, BN folded) + bf16 plane epilogue
__global__ __launch_bounds__(256) void k_mlp1(
    const float* __restrict__ h0,
    const float* __restrict__ w1, const float* __restrict__ cb1,
    const float* __restrict__ w2, const float* __restrict__ cb2,
    const float* __restrict__ w3, const float* __restrict__ cb3,
    const float* __restrict__ bn1g, const float* __restrict__ bn1b,
    const float* __restrict__ bn1m, const float* __restrict__ bn1v,
    const float* __restrict__ bn2g, const float* __restrict__ bn2b,
    const float* __restrict__ bn2m, const float* __restrict__ bn2v,
    const float* __restrict__ bn3g, const float* __restrict__ bn3b,
    const float* __restrict__ bn3m, const float* __restrict__ bn3v,
    float* __restrict__ h3out,
    unsigned short* __restrict__ h3hi, unsigned short* __restrict__ h3lo) {
  __shared__ float W1[144], W2[768], W3[4096];
  __shared__ float S1[12], F1[12], S2[64], F2[64], S3[64], F3[64];
  __shared__ float h0s[64][12];
  __shared__ float A2[64][65];
  const int tid = threadIdx.x;
  for (int i = tid; i < 144; i += 256) W1[i] = w1[i];
  for (int i = tid; i < 768; i += 256) W2[i] = w2[i];
  for (int i = tid; i < 4096; i += 256) W3[i] = w3[i];
  if (tid < 12) {
    float s = bn1g[tid] * rsqrtf(bn1v[tid] + 1e-3f);
    S1[tid] = s; F1[tid] = (cb1[tid] - bn1m[tid]) * s + bn1b[tid];
  }
  if (tid < 64) {
    float s2 = bn2g[tid] * rsqrtf(bn2v[tid] + 1e-3f);
    S2[tid] = s2; F2[tid] = (cb2[tid] - bn2m[tid]) * s2 + bn2b[tid];
    float s3 = bn3g[tid] * rsqrtf(bn3v[tid] + 1e-3f);
    S3[tid] = s3; F3[tid] = (cb3[tid] - bn3m[tid]) * s3 + bn3b[tid];
  }
  const int p0 = blockIdx.x * 64;
  for (int i = tid; i < 64 * 12; i += 256)
    h0s[i / 12][i % 12] = h0[(size_t)p0 * 12 + i];
  __syncthreads();
  const int pl = tid >> 2;
  const int q = tid & 3;
  float v1[12];
#pragma unroll
  for (int o = 0; o < 12; ++o) {
    float a = 0.f;
#pragma unroll
    for (int i = 0; i < 12; ++i) a = fmaf(h0s[pl][i], W1[i * 12 + o], a);
    v1[o] = fmaxf(fmaf(a, S1[o], F1[o]), 0.f);
  }
#pragma unroll
  for (int o = 0; o < 16; ++o) {
    int oo = q * 16 + o;
    float a = 0.f;
#pragma unroll
    for (int i = 0; i < 12; ++i) a = fmaf(v1[i], W2[i * 64 + oo], a);
    A2[pl][oo] = fmaxf(fmaf(a, S2[oo], F2[oo]), 0.f);
  }
  __syncthreads();
  float acc[16];
#pragma unroll
  for (int o = 0; o < 16; ++o) acc[o] = 0.f;
  for (int i = 0; i < 64; ++i) {
    float xv = A2[pl][i];
#pragma unroll
    for (int o = 0; o < 16; ++o) acc[o] = fmaf(xv, W3[i * 64 + q * 16 + o], acc[o]);
  }
  float vals[16];
#pragma unroll
  for (int o = 0; o < 16; ++o) {
    int oo = q * 16 + o;
    vals[o] = fmaxf(fmaf(acc[o], S3[oo], F3[oo]), 0.f);
  }
  const size_t rowo = (size_t)(p0 + pl) * 64 + q * 16;
  float* orow = h3out + rowo;
#pragma unroll
  for (int o4 = 0; o4 < 4; ++o4)
    *(float4*)&orow[4 * o4] = make_float4(vals[4 * o4], vals[4 * o4 + 1],
                                          vals[4 * o4 + 2], vals[4 * o4 + 3]);
  bf16x8 hv0, hv1, lv0, lv1;
#pragma unroll
  for (int o = 0; o < 8; ++o) {
    unsigned short hb = f2bf(vals[o]);
    hv0[o] = (short)hb; lv0[o] = (short)f2bf(vals[o] - bf2f(hb));
    unsigned short hb1 = f2bf(vals[8 + o]);
    hv1[o] = (short)hb1; lv1[o] = (short)f2bf(vals[8 + o] - bf2f(hb1));
  }
  *(bf16x8*)&h3hi[rowo] = hv0; *(bf16x8*)&h3hi[rowo + 8] = hv1;
  *(bf16x8*)&h3lo[rowo] = lv0; *(bf16x8*)&h3lo[rowo + 8] = lv1;
}

// ---------------------------------------------------------------- sq norms
template <int C>
__global__ __launch_bounds__(256) void k_sqnorm(const float* __restrict__ h,
                                                float* __restrict__ sq) {
  const int p = blockIdx.x * 256 + threadIdx.x;
  const float* row = h + (size_t)p * C;
  float a = 0.f;
#pragma unroll
  for (int i = 0; i < C; ++i) a = fmaf(row[i], row[i], a);
  sq[p] = a;
}

// ---------------------------------------------------------------- FUSED knn v4 (R11-proven): MFMA dist -> LDS -> ballot-bisection select
#define DSTRIDE 2052
template <int C>
__global__ __launch_bounds__(1024, 4) void k_knn_fused(
    const unsigned short* __restrict__ hi, const unsigned short* __restrict__ lo,
    const float* __restrict__ sq, const float* __restrict__ h,
    unsigned short* __restrict__ mhi, unsigned short* __restrict__ mlo) {
  __shared__ float dmat[16][DSTRIDE];
  __shared__ unsigned nidx[16][16];
  const int tid = threadIdx.x, lane = tid & 63, w = tid >> 6;
  const int f = blockIdx.x;
  const int g = ((f & 7) << 8) | (f >> 3);
  const int b = g >> 7;
  const int q0 = (g & 127) * 16;
  const size_t base = (size_t)b * NPTS * C;
  const float* __restrict__ sqb = sq + (size_t)b * NPTS;
  const int r = lane & 15, ks = (lane >> 4) * 8;
  const unsigned short* Ah = hi + base + (size_t)(q0 + r) * C + ks;
  const unsigned short* Al = lo + base + (size_t)(q0 + r) * C + ks;
  float sqq[4];
#pragma unroll
  for (int r2 = 0; r2 < 4; ++r2) sqq[r2] = sqb[q0 + (lane >> 4) * 4 + r2];

  // ---- phase 1: wave w -> candidates [w*128, w*128+128)
  {
    const int m0 = w * 128;
    const unsigned short* Bh = hi + base + (size_t)(m0 + r) * C + ks;
    const unsigned short* Bl = lo + base + (size_t)(m0 + r) * C + ks;
    f32x4 acc[8];
#pragma unroll
    for (int s = 0; s < 8; ++s) acc[s] = (f32x4){0.f, 0.f, 0.f, 0.f};
#pragma unroll
    for (int kk = 0; kk < C; kk += 32) {
      bf16x8 ah = *(const bf16x8*)(Ah + kk);
      bf16x8 al = *(const bf16x8*)(Al + kk);
#pragma unroll
      for (int s = 0; s < 8; ++s) {
        bf16x8 bh = *(const bf16x8*)(Bh + (size_t)s * 16 * C + kk);
        bf16x8 bl = *(const bf16x8*)(Bl + (size_t)s * 16 * C + kk);
        acc[s] = __builtin_amdgcn_mfma_f32_16x16x32_bf16(ah, bh, acc[s], 0, 0, 0);
        acc[s] = __builtin_amdgcn_mfma_f32_16x16x32_bf16(ah, bl, acc[s], 0, 0, 0);
        acc[s] = __builtin_amdgcn_mfma_f32_16x16x32_bf16(al, bh, acc[s], 0, 0, 0);
      }
    }
#pragma unroll
    for (int s = 0; s < 8; ++s) {
      const int col = m0 + s * 16 + (lane & 15);
      float smc = sqb[col];
#pragma unroll
      for (int r2 = 0; r2 < 4; ++r2)
        dmat[(lane >> 4) * 4 + r2][col] = fmaf(-2.f, acc[s][r2], sqq[r2] + smc);
    }
  }
  __syncthreads();

  // ---- phase 2: wave w selects query w (ballot-bisection)
  const float* __restrict__ hbp = h + base;
  const int q = q0 + w;
  uint64_t s0 = ~0ull, s1 = ~0ull, s2 = ~0ull, s3 = ~0ull;
#pragma unroll
  for (int t = 0; t < 8; ++t) {
    float4 dv = *(const float4*)&dmat[w][t * 256 + 4 * lane];
    const unsigned mb = (unsigned)(t * 256 + 4 * lane);
    pool_insert(((uint64_t)f2sort(dv.x) << 32) | (mb + 0), s0, s1, s2, s3);
    pool_insert(((uint64_t)f2sort(dv.y) << 32) | (mb + 1), s0, s1, s2, s3);
    pool_insert(((uint64_t)f2sort(dv.z) << 32) | (mb + 2), s0, s1, s2, s3);
    pool_insert(((uint64_t)f2sort(dv.w) << 32) | (mb + 3), s0, s1, s2, s3);
  }
  const unsigned h0 = (unsigned)(s0 >> 32), m0i = (unsigned)s0;
  const unsigned h1 = (unsigned)(s1 >> 32), m1i = (unsigned)s1;
  const unsigned h2 = (unsigned)(s2 >> 32), m2i = (unsigned)s2;
  const unsigned h3 = (unsigned)(s3 >> 32), m3i = (unsigned)s3;
  unsigned H = 0;
#pragma unroll 1
  for (int bit = 31; bit >= 0; --bit) {
    unsigned tr = H | (1u << bit);
    int c = __popcll(__ballot(h0 < tr)) + __popcll(__ballot(h1 < tr)) +
            __popcll(__ballot(h2 < tr)) + __popcll(__ballot(h3 < tr));
    if (c < 16) H = tr;
  }
  const int cs = __popcll(__ballot(h0 < H)) + __popcll(__ballot(h1 < H)) +
                 __popcll(__ballot(h2 < H)) + __popcll(__ballot(h3 < H));
  const int rneed = 16 - cs;
  const bool e0 = (h0 == H), e1 = (h1 == H), e2 = (h2 == H), e3 = (h3 == H);
  const int gsz = __popcll(__ballot(e0)) + __popcll(__ballot(e1)) +
                  __popcll(__ballot(e2)) + __popcll(__ballot(e3));
  unsigned I = 0xFFFFFFFFu;
  if (gsz > rneed) {
    unsigned Iv = 0;
#pragma unroll 1
    for (int bit = 10; bit >= 0; --bit) {
      unsigned tr = Iv | (1u << bit);
      int c2 = __popcll(__ballot(e0 && m0i < tr)) + __popcll(__ballot(e1 && m1i < tr)) +
               __popcll(__ballot(e2 && m2i < tr)) + __popcll(__ballot(e3 && m3i < tr));
      if (c2 < rneed) Iv = tr;
    }
    I = Iv;
  }
  const bool sel0 = (h0 < H) | (e0 & (m0i <= I));
  const bool sel1 = (h1 < H) | (e1 & (m1i <= I));
  const bool sel2 = (h2 < H) | (e2 & (m2i <= I));
  const bool sel3 = (h3 < H) | (e3 & (m3i <= I));
  const int nsel = (int)sel0 + sel1 + sel2 + sel3;
  float g0 = -3.4e38f, g1 = -3.4e38f;
  if (__ballot(nsel == 4) == 0ull) {
    unsigned long long bm;
    int bpos = 0;
    bm = __ballot(sel0); if (sel0) nidx[w][bpos + mbcnt64(bm)] = m0i; bpos += __popcll(bm);
    bm = __ballot(sel1); if (sel1) nidx[w][bpos + mbcnt64(bm)] = m1i; bpos += __popcll(bm);
    bm = __ballot(sel2); if (sel2) nidx[w][bpos + mbcnt64(bm)] = m2i; bpos += __popcll(bm);
    bm = __ballot(sel3); if (sel3) nidx[w][bpos + mbcnt64(bm)] = m3i;
#pragma unroll
    for (int rr = 0; rr < 16; ++rr) {
      unsigned m = nidx[w][rr];
      const float* row = hbp + (size_t)m * C;
      g0 = fmaxf(g0, row[lane]);
      if (C == 128) g1 = fmaxf(g1, row[64 + lane]);
    }
  } else {
    unsigned mask = 0u;
#pragma unroll 1
    for (int rr = 0; rr < 16; ++rr) {
      float vmin = 3.4e38f;
      int mmin = 0x7fffffff;
#pragma unroll
      for (int j = 0; j < 32; ++j) {
        const int m = (j >> 2) * 256 + 4 * lane + (j & 3);
        float dj = dmat[w][m];
        bool ok = !((mask >> j) & 1u) && (dj < vmin);
        if (ok) { vmin = dj; mmin = m; }
      }
#pragma unroll
      for (int s = 1; s < 64; s <<= 1) {
        float ov = __shfl_xor(vmin, s, 64);
        int om = __shfl_xor(mmin, s, 64);
        if (ov < vmin || (ov == vmin && om < mmin)) { vmin = ov; mmin = om; }
      }
      if (lane == ((mmin >> 2) & 63)) mask |= 1u << (((mmin >> 8) << 2) | (mmin & 3));
      const float* row = hbp + (size_t)mmin * C;
      g0 = fmaxf(g0, row[lane]);
      if (C == 128) g1 = fmaxf(g1, row[64 + lane]);
    }
  }
  const size_t orow = base + (size_t)q * C;
  unsigned short h0b = f2bf(g0);
  mhi[orow + lane] = h0b;
  mlo[orow + lane] = f2bf(g0 - bf2f(h0b));
  if (C == 128) {
    unsigned short h1b = f2bf(g1);
    mhi[orow + 64 + lane] = h1b;
    mlo[orow + 64 + lane] = f2bf(g1 - bf2f(h1b));
  }
}

// ---------------------------------------------------------------- combine denses -> W^T bf16 planes + bias
__global__ __launch_bounds__(256) void k_combine_t(const float* __restrict__ lw,
                                                   const float* __restrict__ lb,
                                                   const float* __restrict__ cw,
                                                   const float* __restrict__ cb,
                                                   unsigned short* __restrict__ wthi,
                                                   unsigned short* __restrict__ wtlo,
                                                   float* __restrict__ bc, int K, int M) {
  const int id = blockIdx.x * 256 + threadIdx.x;
  if (id < K * M) {
    int i = id / M, o = id % M;
    float a = 0.f;
    for (int k = 0; k < K; ++k) a = fmaf(lw[i * K + k], cw[k * M + o], a);
    unsigned short hb = f2bf(a);
    wthi[(size_t)o * K + i] = hb;
    wtlo[(size_t)o * K + i] = f2bf(a - bf2f(hb));
  }
  if (id < M) {
    float a = cb[id];
    for (int k = 0; k < K; ++k) a = fmaf(lb[k], cw[k * M + id], a);
    bc[id] = a;
  }
}

// ---------------------------------------------------------------- MFMA apply RELU (g1): 64 rows/block
template <int K, int M>
__global__ __launch_bounds__(256) void k_apply_relu(
    const unsigned short* __restrict__ Ah, const unsigned short* __restrict__ Al,
    const unsigned short* __restrict__ Wh, const unsigned short* __restrict__ Wl,
    const float* __restrict__ bias, float* __restrict__ fout,
    unsigned short* __restrict__ phi, unsigned short* __restrict__ plo) {
  const int tid = threadIdx.x, lane = tid & 63, w = tid >> 6;
  const int q0 = blockIdx.x * 64 + w * 16;
  const int m0 = blockIdx.y * 128;
  const int r = lane & 15, ks = (lane >> 4) * 8;
  const unsigned short* ap_h = Ah + (size_t)(q0 + r) * K + ks;
  const unsigned short* ap_l = Al + (size_t)(q0 + r) * K + ks;
  const unsigned short* bp_h = Wh + (size_t)(m0 + r) * K + ks;
  const unsigned short* bp_l = Wl + (size_t)(m0 + r) * K + ks;
  f32x4 acc[8];
#pragma unroll
  for (int mt = 0; mt < 8; ++mt) acc[mt] = (f32x4){0.f, 0.f, 0.f, 0.f};
#pragma unroll
  for (int kk = 0; kk < K; kk += 32) {
    bf16x8 ah = *(const bf16x8*)(ap_h + kk);
    bf16x8 al = *(const bf16x8*)(ap_l + kk);
#pragma unroll
    for (int mt = 0; mt < 8; ++mt) {
      bf16x8 bh = *(const bf16x8*)(bp_h + (size_t)mt * 16 * K + kk);
      bf16x8 bl = *(const bf16x8*)(bp_l + (size_t)mt * 16 * K + kk);
      acc[mt] = __builtin_amdgcn_mfma_f32_16x16x32_bf16(ah, bh, acc[mt], 0, 0, 0);
      acc[mt] = __builtin_amdgcn_mfma_f32_16x16x32_bf16(ah, bl, acc[mt], 0, 0, 0);
      acc[mt] = __builtin_amdgcn_mfma_f32_16x16x32_bf16(al, bh, acc[mt], 0, 0, 0);
    }
  }
#pragma unroll
  for (int mt = 0; mt < 8; ++mt) {
    const int col = m0 + mt * 16 + (lane & 15);
    const float bv = bias[col];
#pragma unroll
    for (int r2 = 0; r2 < 4; ++r2) {
      const int row = q0 + (lane >> 4) * 4 + r2;
      float v = fmaxf(acc[mt][r2] + bv, 0.f);
      const size_t idx = (size_t)row * M + col;
      fout[idx] = v;
      unsigned short hb = f2bf(v);
      phi[idx] = hb;
      plo[idx] = f2bf(v - bf2f(hb));
    }
  }
}

// ---------------------------------------------------------------- MFMA apply COLMAX (g2): 256 rows/block, W staged in LDS
// K=128, M=1024; grid (128, 8); P[128][1024]
#define WSTRIDE 136
__global__ __launch_bounds__(256, 2) void k_apply_colmax(
    const unsigned short* __restrict__ Ah, const unsigned short* __restrict__ Al,
    const unsigned short* __restrict__ Wh, const unsigned short* __restrict__ Wl,
    const float* __restrict__ bias, float* __restrict__ P) {
  constexpr int K = 128, M = 1024;
  __shared__ unsigned short Bh_s[128 * WSTRIDE];
  __shared__ unsigned short Bl_s[128 * WSTRIDE];
  __shared__ float cm[4][128];
  const int tid = threadIdx.x, lane = tid & 63, w = tid >> 6;
  const int rblk = blockIdx.x;        // 256-row block
  const int m0 = blockIdx.y * 128;    // col block
  const int r = lane & 15, ks = (lane >> 4) * 8;
  // stage W^T tile (rows m0..m0+128) into LDS, padded stride
  for (int i = tid; i < 128 * 16; i += 256) {
    int row = i >> 4, c8 = (i & 15) * 8;
    *(bf16x8*)&Bh_s[row * WSTRIDE + c8] = *(const bf16x8*)&Wh[(size_t)(m0 + row) * K + c8];
    *(bf16x8*)&Bl_s[row * WSTRIDE + c8] = *(const bf16x8*)&Wl[(size_t)(m0 + row) * K + c8];
  }
  __syncthreads();
  const int q0 = rblk * 256 + w * 64;  // wave owns 64 rows
  f32x4 acc[4][8];
#pragma unroll
  for (int st = 0; st < 4; ++st)
#pragma unroll
    for (int mt = 0; mt < 8; ++mt) acc[st][mt] = (f32x4){0.f, 0.f, 0.f, 0.f};
#pragma unroll
  for (int kk = 0; kk < K; kk += 32) {
    bf16x8 bh[8], bl[8];
#pragma unroll
    for (int mt = 0; mt < 8; ++mt) {
      bh[mt] = *(const bf16x8*)&Bh_s[(mt * 16 + r) * WSTRIDE + ks + kk];
      bl[mt] = *(const bf16x8*)&Bl_s[(mt * 16 + r) * WSTRIDE + ks + kk];
    }
#pragma unroll
    for (int st = 0; st < 4; ++st) {
      const unsigned short* ap_h = Ah + (size_t)(q0 + st * 16 + r) * K + ks + kk;
      const unsigned short* ap_l = Al + (size_t)(q0 + st * 16 + r) * K + ks + kk;
      bf16x8 ah = *(const bf16x8*)ap_h;
      bf16x8 al = *(const bf16x8*)ap_l;
#pragma unroll
      for (int mt = 0; mt < 8; ++mt) {
        acc[st][mt] = __builtin_amdgcn_mfma_f32_16x16x32_bf16(ah, bh[mt], acc[st][mt], 0, 0, 0);
        acc[st][mt] = __builtin_amdgcn_mfma_f32_16x16x32_bf16(ah, bl[mt], acc[st][mt], 0, 0, 0);
        acc[st][mt] = __builtin_amdgcn_mfma_f32_16x16x32_bf16(al, bh[mt], acc[st][mt], 0, 0, 0);
      }
    }
  }
  // colmax epilogue: combine subtiles in-register, then shfl, then 4-wave LDS reduce
#pragma unroll
  for (int mt = 0; mt < 8; ++mt) {
    float v = -3.4e38f;
#pragma unroll
    for (int st = 0; st < 4; ++st) {
      v = fmaxf(v, fmaxf(fmaxf(acc[st][mt][0], acc[st][mt][1]),
                         fmaxf(acc[st][mt][2], acc[st][mt][3])));
    }
    v = fmaxf(v, __shfl_xor(v, 16, 64));
    v = fmaxf(v, __shfl_xor(v, 32, 64));
    cm[w][mt * 16 + (lane & 15)] = v;
  }
  __syncthreads();
  if (tid < 128) {
    float m = fmaxf(fmaxf(cm[0][tid], cm[1][tid]), fmaxf(cm[2][tid], cm[3][tid]));
    P[(size_t)rblk * M + m0 + tid] = m + bias[m0 + tid];
  }
}

// ---------------------------------------------------------------- reduce P[128][1024] -> gmax[16][1024] (8 rowtiles per batch)
__global__ __launch_bounds__(256) void k_reduce_max(const float* __restrict__ P,
                                                    float* __restrict__ gmax) {
  const int b = blockIdx.x, tid = threadIdx.x;
  for (int c = tid; c < 1024; c += 256) {
    float m = P[(size_t)(b * 8) * 1024 + c];
    for (int rt = 1; rt < 8; ++rt)
      m = fmaxf(m, P[(size_t)(b * 8 + rt) * 1024 + c]);
    gmax[b * 1024 + c] = m;
  }
}

// ---------------------------------------------------------------- head part 1: hid = relu(gmax*W4+b4)
__global__ __launch_bounds__(256) void k_head1(const float* __restrict__ gmax,
                                               const float* __restrict__ w4,
                                               const float* __restrict__ b4,
                                               float* __restrict__ hid) {
  const int b = blockIdx.y, c0 = blockIdx.x * 64;
  const int tid = threadIdx.x;
  const int c = tid & 63, iq = tid >> 6;
  __shared__ float xs[1024];
  __shared__ float red[4][64];
  for (int i = tid; i < 1024; i += 256) xs[i] = gmax[b * 1024 + i];
  __syncthreads();
  float a = 0.f;
  for (int i = iq * 256; i < iq * 256 + 256; ++i)
    a = fmaf(xs[i], w4[(size_t)i * 1024 + c0 + c], a);
  red[iq][c] = a;
  __syncthreads();
  if (tid < 64) {
    float v = red[0][tid] + red[1][tid] + red[2][tid] + red[3][tid];
    hid[b * 1024 + c0 + tid] = fmaxf(v + b4[c0 + tid], 0.f);
  }
}

// ---------------------------------------------------------------- head part 2: out = hid*W5+b5
__global__ __launch_bounds__(256) void k_head2(const float* __restrict__ hid,
                                               const float* __restrict__ w5,
                                               const float* __restrict__ b5,
                                               float* __restrict__ out) {
  const int b = blockIdx.y, c0 = blockIdx.x * 64;
  const int tid = threadIdx.x;
  const int c = tid & 63, iq = tid >> 6;
  __shared__ float xs[1024];
  __shared__ float red[4][64];
  for (int i = tid; i < 1024; i += 256) xs[i] = hid[b * 1024 + i];
  __syncthreads();
  float a = 0.f;
  for (int i = iq * 256; i < iq * 256 + 256; ++i)
    a = fmaf(xs[i], w5[(size_t)i * 512 + c0 + c], a);
  red[iq][c] = a;
  __syncthreads();
  if (tid < 64) {
    float v = red[0][tid] + red[1][tid] + red[2][tid] + red[3][tid];
    out[(size_t)b * 512 + c0 + tid] = v + b5[c0 + tid];
  }
}

// ----------------------------------------------------------------
extern "C" void kernel_launch(void* const* d_in, const int* in_sizes, int n_in,
                              void* d_out, int out_size, void* d_ws, size_t ws_size,
                              hipStream_t stream) {
  (void)in_sizes; (void)n_in; (void)out_size; (void)ws_size;
  const float* x = (const float*)d_in[0];
  const float* w1 = (const float*)d_in[1];  const float* b1 = (const float*)d_in[2];
  const float* w2 = (const float*)d_in[3];  const float* b2 = (const float*)d_in[4];
  const float* w3 = (const float*)d_in[5];  const float* b3 = (const float*)d_in[6];
  const float* g1lw = (const float*)d_in[7];  const float* g1lb = (const float*)d_in[8];
  const float* g1cw = (const float*)d_in[9];  const float* g1cb = (const float*)d_in[10];
  const float* g2lw = (const float*)d_in[11]; const float* g2lb = (const float*)d_in[12];
  const float* g2cw = (const float*)d_in[13]; const float* g2cb = (const float*)d_in[14];
  const float* w4 = (const float*)d_in[15]; const float* b4 = (const float*)d_in[16];
  const float* w5 = (const float*)d_in[17]; const float* b5 = (const float*)d_in[18];
  const float* bn1g = (const float*)d_in[19]; const float* bn1b = (const float*)d_in[20];
  const float* bn1m = (const float*)d_in[21]; const float* bn1v = (const float*)d_in[22];
  const float* bn2g = (const float*)d_in[23]; const float* bn2b = (const float*)d_in[24];
  const float* bn2m = (const float*)d_in[25]; const float* bn2v = (const float*)d_in[26];
  const float* bn3g = (const float*)d_in[27]; const float* bn3b = (const float*)d_in[28];
  const float* bn3m = (const float*)d_in[29]; const float* bn3v = (const float*)d_in[30];

  float* ws = (float*)d_ws;
  size_t off = 0;
  auto alloc = [&](size_t n) { float* p = ws + off; off += (n + 63) & ~(size_t)63; return p; };
  float* slotA = alloc(16u * 2048 * 128);   // h0 then h4 f32
  float* slotB = alloc(16u * 2048 * 64);    // h3 f32
  float* sqv  = alloc(16u * 2048);
  unsigned short* hi_h = (unsigned short*)alloc(16u * 2048 * 64);
  unsigned short* lo_h = (unsigned short*)alloc(16u * 2048 * 64);
  unsigned short* mhi = (unsigned short*)alloc(16u * 2048 * 64);
  unsigned short* mlo = (unsigned short*)alloc(16u * 2048 * 64);
  unsigned short* wthi = (unsigned short*)alloc(65536);
  unsigned short* wtlo = (unsigned short*)alloc(65536);
  float* bc   = alloc(1024);
  float* P    = alloc(128u * 1024);
  float* gm   = alloc(16u * 1024);
  float* hid  = alloc(16u * 1024);

  // 1: knn on xyz + covariance -> h0[B,N,12]
  k_knn1_cov<<<dim3(512, 16), 256, 0, stream>>>(x, slotA);
  // 2: MLP1 -> h3 f32 + bf16 planes
  k_mlp1<<<512, 256, 0, stream>>>(slotA, w1, b1, w2, b2, w3, b3,
                                  bn1g, bn1b, bn1m, bn1v,
                                  bn2g, bn2b, bn2m, bn2v,
                                  bn3g, bn3b, bn3m, bn3v, slotB, hi_h, lo_h);
  // 3: knn(64) fused -> m1 planes
  k_sqnorm<64><<<128, 256, 0, stream>>>(slotB, sqv);
  k_knn_fused<64><<<2048, 1024, 0, stream>>>(hi_h, lo_h, sqv, slotB, mhi, mlo);
  // 4: g1 combined dense 64->128 + relu -> h4 f32 + planes (MFMA)
  k_combine_t<<<32, 256, 0, stream>>>(g1lw, g1lb, g1cw, g1cb, wthi, wtlo, bc, 64, 128);
  k_apply_relu<64, 128><<<dim3(512, 1), 256, 0, stream>>>(
      mhi, mlo, wthi, wtlo, bc, slotA, hi_h, lo_h);
  // 5: knn(128) fused -> m2 planes
  k_sqnorm<128><<<128, 256, 0, stream>>>(slotA, sqv);
  k_knn_fused<128><<<2048, 1024, 0, stream>>>(hi_h, lo_h, sqv, slotA, mhi, mlo);
  // 6: g2 combined dense 128->1024 + colmax -> P (MFMA, W in LDS, 256 rows/block)
  k_combine_t<<<512, 256, 0, stream>>>(g2lw, g2lb, g2cw, g2cb, wthi, wtlo, bc, 128, 1024);
  k_apply_colmax<<<dim3(128, 8), 256, 0, stream>>>(mhi, mlo, wthi, wtlo, bc, P);
  // 7: reduce -> gmax[16][1024]
  k_reduce_max<<<16, 256, 0, stream>>>(P, gm);
  // 8: head -> out[16][512]
  k_head1<<<dim3(16, 16), 256, 0, stream>>>(gm, w4, b4, hid);
  k_head2<<<dim3(8, 16), 256, 0, stream>>>(hid, w5, b5, (float*)d_out);
}